// Round 13
// baseline (683.369 us; speedup 1.0000x reference)
//
#include <hip/hip_runtime.h>
#include <hip/hip_fp16.h>
#include <stdint.h>

#define NEG_ (-1e9f)
#define CPB 16   // 32-row chunks per block; grid = 4096/CPB = 256 (1 block/CU)

typedef _Float16 f16x8 __attribute__((ext_vector_type(8)));
typedef _Float16 f16x4 __attribute__((ext_vector_type(4)));
typedef float    f32x4 __attribute__((ext_vector_type(4)));

__device__ __forceinline__ float fast_tanh(float x) {
  float e = __expf(2.0f * x);
  return (e - 1.0f) * __builtin_amdgcn_rcpf(e + 1.0f);
}

// Raw workgroup barrier with LDS visibility ONLY (lgkmcnt(0)); does NOT
// drain vmcnt, so in-flight DMAs survive it.
__device__ __forceinline__ void bar_lds() {
  asm volatile("s_waitcnt lgkmcnt(0)" ::: "memory");
  __builtin_amdgcn_s_barrier();
  __builtin_amdgcn_sched_barrier(0);
}

// ---------------------------------------------------------------------------
// K0: repack W [512 o][512 h] fp32 -> f16 in MFMA A-fragment stream order.
// seg = w*64 + ks*4 + io  (1KB each); w in 0..7 is the owning wave.
// ---------------------------------------------------------------------------
__global__ __launch_bounds__(256) void k0_cvt_w(const float* __restrict__ W,
                                                __half* __restrict__ Wws) {
  int g = blockIdx.x * 256 + threadIdx.x;
  int lane = g & 63;
  int seg  = g >> 6;
  int io = seg & 3, ks = (seg >> 2) & 15, w = seg >> 6;
  int o = w * 64 + io * 16 + (lane & 15);
  int k = ks * 32 + (lane >> 4) * 8;
  const float2* src = (const float2*)(W + (size_t)o * 512 + k);
  __half2 h[4];
#pragma unroll
  for (int j = 0; j < 4; ++j) { float2 f = src[j]; h[j] = __floats2half2_rn(f.x, f.y); }
  uint4 u;
  u.x = *(uint32_t*)&h[0]; u.y = *(uint32_t*)&h[1];
  u.z = *(uint32_t*)&h[2]; u.w = *(uint32_t*)&h[3];
  *(uint4*)(Wws + (size_t)seg * 512 + (size_t)lane * 8) = u;
}

// ---------------------------------------------------------------------------
// K1 (round-13): DMA double-buffered pipeline.
// Evidence chain: R12 proved DMA staging is clean (WRITE 4.7MB) yet 188 us
// == R3/R8 -> serial stage/compute phases are the invariant bottleneck,
// not traffic. R4-6's pipeline schedule was right but its register payload
// spilled. Here the payload is ZERO (DMA) and the stage flies under the
// epilogue:
//   per tile: [A-ring MFMA ks0..13] [DMA tile i+1 -> Xs (after last aload:
//   in-order vmcnt => ks14/15 A-waits are counted vmcnt(N), no drain)]
//   [MFMA ks14,15] [epilogue, lgkm-only barriers] [vmcnt(0): DMA landed]
//   [LDS repack Xs fp32 -> Xh[cur^1] f16 XOR-swizzled, ~0.3us] [bar]
// The repack removes all f32->f16 cvts from the MFMA loop and restores the
// verified conflict-free f16 fragment reads (R3/R8 layout). A-ring depth-3.
// bias/ctx/mask hoisted: any epilogue VMEM read after the DMAs would drain
// them on its wait. LDS 151 KB -> 1 block/CU.
// ---------------------------------------------------------------------------
__global__ __launch_bounds__(512, 2) void k1_scores(
    const float* __restrict__ enc, const int* __restrict__ msk,
    const float* __restrict__ bias, const float* __restrict__ ctx,
    const __half* __restrict__ Wws, float* __restrict__ scores,
    float* __restrict__ psum, float* __restrict__ mpart,
    float* __restrict__ lpart) {
  __shared__ __align__(16) float  Xs[32 * 512];      // 64 KB fp32 DMA landing
  __shared__ __align__(16) __half Xh[2][32 * 512];   // 2 x 32 KB f16 swizzled
  __shared__ __align__(16) float pred[8 * 512];      // 16 KB
  __shared__ float sred[256];
  __shared__ float pbuf[32];
  __shared__ int   mbuf[512];

  const int t = threadIdx.x;
  const int w = t >> 6;
  const int lane = t & 63;
  const int quad = lane >> 4;
  const int l15 = lane & 15;
  const int ch0 = blockIdx.x * CPB;

  // ---- A-fragment register ring (depth-3) from L2-resident Wws ----
  f16x8 abuf[4][4];
  auto aload = [&](int slot, int ks) {
    const f16x8* sp = (const f16x8*)(Wws +
        ((size_t)(w * 64 + ks * 4) * 512) + (size_t)lane * 8);
#pragma unroll
    for (int io = 0; io < 4; ++io) abuf[slot][io] = sp[io * 64];
  };

  // ---- DMA: 8 x global_load_lds(16B)/wave, strictly linear src+dst ----
  auto dma = [&](int ch) {
    const float* base = enc + (size_t)ch * (32 * 512);
#pragma unroll
    for (int it = 0; it < 8; ++it) {
      int seg = it * 8 + w;                 // 0..63, 1KB each
      const float* src = base + (size_t)seg * 256 + lane * 4;
      float* dst = &Xs[seg * 256];          // wave-uniform base
      __builtin_amdgcn_global_load_lds(
          (const __attribute__((address_space(1))) void*)src,
          (__attribute__((address_space(3))) void*)dst, 16, 0, 0);
    }
  };

  // ---- LDS repack: Xs fp32 -> Xh[buf] f16, XOR-swizzled 16B chunks.
  //      read: 64 lanes fully contiguous (conflict-free); write: b64. ----
  auto repack = [&](int buf) {
#pragma unroll
    for (int p = 0; p < 8; ++p) {
      int seg = w * 8 + p;                  // 0..63
      int s = seg >> 1, half = seg & 1;
      f32x4 xv = *(const f32x4*)&Xs[seg * 256 + lane * 4];
      f16x4 hv;
      hv[0] = (_Float16)xv[0]; hv[1] = (_Float16)xv[1];
      hv[2] = (_Float16)xv[2]; hv[3] = (_Float16)xv[3];
      int c  = half * 32 + (lane >> 1);     // logical 16B chunk (8 f16)
      int pc = c ^ (s & 7);                 // physical chunk
      *(f16x4*)&Xh[buf][s * 512 + pc * 8 + (lane & 1) * 4] = hv;
    }
  };

  // ---- prologue: hoist all epilogue VMEM reads, stage+repack tile 0 ----
  float4 bq[4], vq[4];
#pragma unroll
  for (int io = 0; io < 4; ++io) {
    int ob = w * 64 + io * 16 + quad * 4;
    bq[io] = *(const float4*)(bias + ob);
    vq[io] = *(const float4*)(ctx + ob);
  }
  mbuf[t] = msk[(size_t)ch0 * 32 + t];
  dma(ch0);
  asm volatile("s_waitcnt vmcnt(0)" ::: "memory");
  bar_lds();
  repack(0);
  bar_lds();

#define MFMA_STEP(ks)                                                        \
  {                                                                          \
    const f16x8* acur = abuf[(ks) & 3];                                      \
    _Pragma("unroll")                                                        \
    for (int is = 0; is < 2; ++is) {                                         \
      int s = is * 16 + l15;                                                 \
      const f16x8 bf = *(const f16x8*)&Xc[s * 512 +                          \
          ((((ks) * 4 + quad) ^ (s & 7)) << 3)];                             \
      _Pragma("unroll")                                                      \
      for (int io = 0; io < 4; ++io)                                         \
        acc[io][is] = __builtin_amdgcn_mfma_f32_16x16x32_f16(                \
            acur[io], bf, acc[io][is], 0, 0, 0);                             \
    }                                                                        \
  }

#pragma unroll 1
  for (int i = 0; i < CPB; ++i) {
    const int ch = ch0 + i;
    const int cur = i & 1;
    const __half* Xc = Xh[cur];

    aload(0, 0); aload(1, 1); aload(2, 2);

    f32x4 acc[4][2];
#pragma unroll
    for (int io = 0; io < 4; ++io)
#pragma unroll
      for (int is = 0; is < 2; ++is) acc[io][is] = (f32x4){0.f, 0.f, 0.f, 0.f};

#pragma unroll
    for (int ks = 0; ks < 14; ++ks) {
      if (ks < 13) aload((ks + 3) & 3, ks + 3);   // last A-load at ks=12
      MFMA_STEP(ks);
    }

    // DMA next tile: after ALL A-loads of this tile (in-order vmcnt);
    // flies under MFMA tail + epilogue.
    __builtin_amdgcn_sched_barrier(0);
    if (i + 1 < CPB) dma(ch + 1);
    __builtin_amdgcn_sched_barrier(0);

    MFMA_STEP(14);
    MFMA_STEP(15);

    // ---- epilogue (all VMEM reads pre-hoisted) ----
    float ps[2] = {0.f, 0.f};
#pragma unroll
    for (int io = 0; io < 4; ++io) {
      float4 b4 = bq[io], v4 = vq[io];
#pragma unroll
      for (int is = 0; is < 2; ++is) {
        const f32x4 a = acc[io][is];
        ps[is] += fast_tanh(a[0] + b4.x) * v4.x + fast_tanh(a[1] + b4.y) * v4.y +
                  fast_tanh(a[2] + b4.z) * v4.z + fast_tanh(a[3] + b4.w) * v4.w;
      }
    }
#pragma unroll
    for (int is = 0; is < 2; ++is) {
      ps[is] += __shfl_xor(ps[is], 16, 64);
      ps[is] += __shfl_xor(ps[is], 32, 64);
    }

    bar_lds();
    if (lane < 16) {
      sred[w * 32 + lane]      = ps[0];
      sred[w * 32 + 16 + lane] = ps[1];
    }
    bar_lds();
    if (t < 32) {   // finalize scores + local softmax stats for 32 rows
      float sc = 0.f;
#pragma unroll
      for (int w2 = 0; w2 < 8; ++w2) sc += sred[w2 * 32 + t];
      size_t row = (size_t)ch * 32 + t;
      float sm = mbuf[i * 32 + t] ? sc : NEG_;
      scores[row] = sm;
      float m = sm;
#pragma unroll
      for (int off = 16; off >= 1; off >>= 1) m = fmaxf(m, __shfl_xor(m, off, 32));
      float p = __expf(sm - m);
      float l = p;
#pragma unroll
      for (int off = 16; off >= 1; off >>= 1) l += __shfl_xor(l, off, 32);
      pbuf[t] = p;
      if (t == 0) { mpart[ch] = m; lpart[ch] = l; }
    }
    bar_lds();

    // ---- psum partial from f16 tile: wave w rows w*4..w*4+3,
    //      lane covers h = lane*8..lane*8+7 (chunk = lane, XOR-deswizzle) ----
    float pacc[8] = {0.f, 0.f, 0.f, 0.f, 0.f, 0.f, 0.f, 0.f};
#pragma unroll
    for (int si = 0; si < 4; ++si) {
      int s2 = w * 4 + si;
      float pv = pbuf[s2];
      const f16x8 xv = *(const f16x8*)&Xc[s2 * 512 + ((lane ^ (s2 & 7)) << 3)];
#pragma unroll
      for (int j = 0; j < 8; ++j) pacc[j] = fmaf(pv, (float)xv[j], pacc[j]);
    }
    {
      float4 lo = {pacc[0], pacc[1], pacc[2], pacc[3]};
      float4 hi = {pacc[4], pacc[5], pacc[6], pacc[7]};
      *(float4*)&pred[w * 512 + lane * 4] = lo;
      *(float4*)&pred[w * 512 + 256 + lane * 4] = hi;
    }
    bar_lds();
    if (t < 128) {
      int half = t & 1, c2 = t >> 1;
      float4 a = {0.f, 0.f, 0.f, 0.f};
#pragma unroll
      for (int w2 = 0; w2 < 8; ++w2) {
        float4 pv = *(const float4*)&pred[w2 * 512 + half * 256 + c2 * 4];
        a.x += pv.x; a.y += pv.y; a.z += pv.z; a.w += pv.w;
      }
      *(float4*)&psum[(size_t)ch * 512 + (size_t)t * 4] = a;
    }

    if (i + 1 < CPB) {
      asm volatile("s_waitcnt vmcnt(0)" ::: "memory");  // DMA landed (covered)
      bar_lds();
      repack(cur ^ 1);
    }
    bar_lds();
  }
#undef MFMA_STEP
}

// ---------------------------------------------------------------------------
// K2 (combine, 512 blocks): block (b,g) recomputes M,Z from the 64 chunk
// stats (L2-hot), rewrites attn slice [g*256, g*256+256), reduces the psum
// h-slice [g*64, g*64+64).
// ---------------------------------------------------------------------------
__global__ __launch_bounds__(256) void k2_combine(
    float* __restrict__ attn, const float* __restrict__ psum,
    const float* __restrict__ mpart, const float* __restrict__ lpart,
    float* __restrict__ out0) {
  const int b = blockIdx.x >> 3, g = blockIdx.x & 7, t = threadIdx.x;
  __shared__ float ml[64], ll[64];
  if (t < 64) { ml[t] = mpart[b * 64 + t]; ll[t] = lpart[b * 64 + t]; }
  __syncthreads();
  float M = -3.4e38f;
#pragma unroll
  for (int i = 0; i < 64; ++i) M = fmaxf(M, ml[i]);
  float Z = 0.f;
#pragma unroll
  for (int i = 0; i < 64; ++i) Z += __expf(ml[i] - M) * ll[i];
  float invZ = 1.0f / Z;

  {
    int s = g * 256 + t;
    float* row = attn + (size_t)b * 2048;
    row[s] = __expf(row[s] - M) * invZ;
  }

  if (t < 64) {
    int h = g * 64 + t;
    float a = 0.f;
#pragma unroll
    for (int c2 = 0; c2 < 64; ++c2) {
      float wv = __expf(ml[c2] - M);
      a = fmaf(wv, psum[((size_t)(b * 64 + c2)) * 512 + h], a);
    }
    out0[(size_t)b * 512 + h] = a * invZ;
  }
}

// ---------------------------------------------------------------------------
extern "C" void kernel_launch(void* const* d_in, const int* in_sizes, int n_in,
                              void* d_out, int out_size, void* d_ws, size_t ws_size,
                              hipStream_t stream) {
  (void)in_sizes; (void)n_in; (void)out_size; (void)ws_size;
  const float* enc  = (const float*)d_in[0];  // [64,2048,512] fp32
  const int*   msk  = (const int*)d_in[1];    // [64,2048] bool->int32
  const float* W    = (const float*)d_in[2];  // [512,512] fp32
  const float* bias = (const float*)d_in[3];  // [512] fp32
  const float* ctx  = (const float*)d_in[4];  // [512] fp32
  float* out0 = (float*)d_out;                // [64,512] weighted output
  float* attn = out0 + 64 * 512;              // [64,2048] scores -> attn (in place)

  __half* Wws  = (__half*)d_ws;                               // 512 KB
  float*  psum = (float*)((char*)d_ws + (512u << 10));        // 8 MB  [4096][512]
  float*  mprt = psum + (size_t)4096 * 512;                   // 16 KB
  float*  lprt = mprt + 4096;                                 // 16 KB

  k0_cvt_w<<<128, 256, 0, stream>>>(W, Wws);
  k1_scores<<<4096 / CPB, 512, 0, stream>>>(enc, msk, bias, ctx, Wws, attn,
                                            psum, mprt, lprt);
  k2_combine<<<512, 256, 0, stream>>>(attn, psum, mprt, lprt, out0);
}